// Round 2
// baseline (40.886 us; speedup 1.0000x reference)
//
#include <hip/hip_runtime.h>

#define BSZ 4
#define CH  64
#define CE  8      // C/8
#define HW  4096

// ---------------------------------------------------------------------------
// Stage 1: fused 1x1 conv (k, q_l, v) + block-local partial reduction of
//   A[b,c,e] = sum_q v[b,c,q]*qg_w[q,e]
//   B[b,c,e] = sum_q v[b,c,q]*k[b,e,q]
//   S[b,c]   = sum_q v[b,c,q]*qg_b[q]
// accumulated into global A/B/S via atomicAdd (zeroed by memset beforehand).
// v never touches global memory.
//
// Block = 320 threads (5 waves). Wave 0 computes k(8)+q_l(8); waves 1..4
// compute 16 v channels each. Weight indices are wave-uniform (readfirstlane)
// so weight loads become s_load + v_fmac with SGPR operand (no LDS broadcast).
// Grid = 256 blocks = 4 batches x 64 column-groups of 64.
// ---------------------------------------------------------------------------
__global__ __launch_bounds__(320) void stage1_kernel(
    const float* __restrict__ x,
    const float* __restrict__ qlw, const float* __restrict__ qlb,
    const float* __restrict__ kw,  const float* __restrict__ kb,
    const float* __restrict__ vw,  const float* __restrict__ vb,
    const float* __restrict__ qgw, const float* __restrict__ qgb,
    float* __restrict__ kbuf, float* __restrict__ qlbuf,
    float* __restrict__ Abuf, float* __restrict__ Bbuf, float* __restrict__ Sbuf)
{
    __shared__ float v_lds[CH][65];   // stride 65 == 1 mod 32 -> conflict-free
    __shared__ float k_lds[CE][64];

    const int tid  = threadIdx.x;
    const int lane = tid & 63;
    const int g    = __builtin_amdgcn_readfirstlane(tid >> 6);  // wave id 0..4
    const int b    = blockIdx.x >> 6;
    const int p0   = (blockIdx.x & 63) << 6;
    const int p    = p0 | lane;

    // column of x in registers (64 VGPRs); tile is 16 KB -> L1-resident for
    // the 4 sibling waves re-reading it.
    float xv[CH];
#pragma unroll
    for (int c = 0; c < CH; ++c) xv[c] = x[((b << 6) + c) * HW + p];

    if (g == 0) {
#pragma unroll
        for (int o = 0; o < CE; ++o) {
            float acc = kb[o];
#pragma unroll
            for (int c = 0; c < CH; ++c) acc += kw[o * CH + c] * xv[c];
            kbuf[((b << 3) + o) * HW + p] = acc;
            k_lds[o][lane] = acc;
        }
#pragma unroll
        for (int o = 0; o < CE; ++o) {
            float acc = qlb[o];
#pragma unroll
            for (int c = 0; c < CH; ++c) acc += qlw[o * CH + c] * xv[c];
            qlbuf[((b << 3) + o) * HW + p] = acc;
        }
    } else {
        const int c0 = (g - 1) << 4;   // scalar
#pragma unroll
        for (int oi = 0; oi < 16; ++oi) {
            const int c = c0 + oi;     // scalar
            float acc = vb[c];
#pragma unroll
            for (int cc = 0; cc < CH; ++cc) acc += vw[c * CH + cc] * xv[cc];
            v_lds[c][lane] = acc;
        }
    }
    __syncthreads();

    // ---- partial reduction over this block's 64 columns ----
    if (g < 4) {
        const int c  = lane;
        const int e0 = g;        // scalar
        const int e1 = g + 4;    // scalar
        float a0 = 0.f, a1 = 0.f, b0 = 0.f, b1 = 0.f;
#pragma unroll
        for (int pp = 0; pp < 64; ++pp) {
            const float vv = v_lds[c][pp];              // bank (lane+pp)%32: free
            a0 += vv * qgw[(p0 + pp) * 8 + e0];         // scalar load
            a1 += vv * qgw[(p0 + pp) * 8 + e1];         // scalar load
            b0 += vv * k_lds[e0][pp];                   // broadcast
            b1 += vv * k_lds[e1][pp];                   // broadcast
        }
        const int base = (((b << 6) + c) << 3);
        atomicAdd(&Abuf[base + e0], a0);
        atomicAdd(&Abuf[base + e1], a1);
        atomicAdd(&Bbuf[base + e0], b0);
        atomicAdd(&Bbuf[base + e1], b1);
    } else {
        const int c = lane;
        float s = 0.f;
#pragma unroll
        for (int pp = 0; pp < 64; ++pp)
            s += v_lds[c][pp] * qgb[p0 + pp];           // scalar load
        atomicAdd(&Sbuf[(b << 6) + c], s);
    }
}

// ---------------------------------------------------------------------------
// Stage 2: out[b,c,p] = gg*(dot8(k_g[b,p,:],A[b,c,:]) + S[b,c])
//                     + gl* dot8(q_l[b,p,:],B[b,c,:]) + x[b,c,p]
// A/B/S indices are wave-uniform -> s_load (SGPR) operands, zero LDS.
// k_g[b,p,e] = kbuf flat at b*32768 + p*8 + e (raw reshape regroup).
// Block = 256 threads = 64 columns x 4 channel-groups of 16; grid = 256.
// ---------------------------------------------------------------------------
__global__ __launch_bounds__(256) void stage2_kernel(
    const float* __restrict__ x,
    const float* __restrict__ kbuf, const float* __restrict__ qlbuf,
    const float* __restrict__ Abuf, const float* __restrict__ Bbuf,
    const float* __restrict__ Sbuf,
    const float* __restrict__ ggp, const float* __restrict__ glp,
    float* __restrict__ out)
{
    const int tid  = threadIdx.x;
    const int lane = tid & 63;
    const int grp  = __builtin_amdgcn_readfirstlane(tid >> 6);  // 0..3
    const int b    = blockIdx.x >> 6;
    const int p    = ((blockIdx.x & 63) << 6) | lane;

    const float gg = ggp[0], gl = glp[0];

    const float* kgp = kbuf + ((size_t)(b << 3) * HW) + ((size_t)p << 3);
    const float4 kg0 = *reinterpret_cast<const float4*>(kgp);
    const float4 kg1 = *reinterpret_cast<const float4*>(kgp + 4);
    const float kg[8] = {kg0.x, kg0.y, kg0.z, kg0.w, kg1.x, kg1.y, kg1.z, kg1.w};
    float ql[8];
#pragma unroll
    for (int e = 0; e < CE; ++e) ql[e] = qlbuf[((b << 3) + e) * HW + p];

    const int c0 = grp << 4;   // scalar
#pragma unroll
    for (int ci = 0; ci < 16; ++ci) {
        const int c = c0 + ci; // scalar
        const int abase = (((b << 6) + c) << 3);
        float aA = 0.f, aB = 0.f;
#pragma unroll
        for (int e = 0; e < CE; ++e) {
            aA += kg[e] * Abuf[abase + e];   // s_load operand
            aB += ql[e] * Bbuf[abase + e];   // s_load operand
        }
        const int idx = ((b << 6) + c) * HW + p;
        out[idx] = gg * (aA + Sbuf[(b << 6) + c]) + gl * aB + x[idx];
    }
}

extern "C" void kernel_launch(void* const* d_in, const int* in_sizes, int n_in,
                              void* d_out, int out_size, void* d_ws, size_t ws_size,
                              hipStream_t stream) {
    const float* x   = (const float*)d_in[0];
    const float* qlw = (const float*)d_in[1];
    const float* qlb = (const float*)d_in[2];
    const float* kw  = (const float*)d_in[3];
    const float* kb  = (const float*)d_in[4];
    const float* vw  = (const float*)d_in[5];
    const float* vb  = (const float*)d_in[6];
    const float* qgw = (const float*)d_in[7];
    const float* qgb = (const float*)d_in[8];
    const float* gg  = (const float*)d_in[9];
    const float* gl  = (const float*)d_in[10];
    float* out = (float*)d_out;

    float* ws    = (float*)d_ws;
    float* Abuf  = ws;                        // 4*64*8 = 2048 f
    float* Bbuf  = Abuf + BSZ * CH * 8;       // 2048 f
    float* Sbuf  = Bbuf + BSZ * CH * 8;       // 256 f
    float* kbuf  = Sbuf + BSZ * CH;           // 4*8*4096 = 131072 f
    float* qlbuf = kbuf + BSZ * CE * HW;      // 131072 f

    // zero the atomic accumulators (A,B,S contiguous: 4352 floats = 17 KB)
    hipMemsetAsync(Abuf, 0, (size_t)(2 * BSZ * CH * 8 + BSZ * CH) * sizeof(float),
                   stream);

    stage1_kernel<<<256, 320, 0, stream>>>(x, qlw, qlb, kw, kb, vw, vb, qgw, qgb,
                                           kbuf, qlbuf, Abuf, Bbuf, Sbuf);
    stage2_kernel<<<256, 256, 0, stream>>>(x, kbuf, qlbuf, Abuf, Bbuf, Sbuf,
                                           gg, gl, out);
}